// Round 2
// baseline (220.723 us; speedup 1.0000x reference)
//
#include <hip/hip_runtime.h>

// NNUE pairwise-embedding sum, algebraically reduced:
//   out[b] = sum_{r,c in L_b} S[x_r][x_c]
// where S[a][b] = sum_d tiles[a][b][d]  (768x768 row-sums, 2.36 MB)
// and L_b = { v in x[b,:] : v < 768, v != 3, (turn==1 || v != 443) }.
// Derivation: out sums all 64 embedding dims, so only row-sums matter;
// the black-side weight flip is exactly inverted by the xb index flip
// (W_b[xb(u),xb(v)] == Z[u,v], Z = white-zeroed tiles), leaving only the
// zero-mask difference: white zeroes row/col 3; black zeroes rows/cols
// {3, 443} in original coords (black-frame 3 == original 443). Fill
// indices (3 / 443) hit zeroed rows, so invalid pairs contribute 0.

#define DIN 768
#define NENT (768 * 768)
#define NB 1024
#define NF 36

// Kernel 1: S[e] = sum of 64 consecutive floats of tiles.
// 16 lanes per entry, each loads one float4 (256 B contiguous per group,
// 1 KB contiguous per wave) -> perfectly coalesced, memory-bound.
__global__ __launch_bounds__(256) void k_rowsum(const float* __restrict__ tiles,
                                                float* __restrict__ S) {
    int tid = blockIdx.x * 256 + threadIdx.x;
    int gid = tid >> 4;            // entry group
    int s   = tid & 15;            // sub-lane within group
    int stride = (gridDim.x * 256) >> 4;
    for (int e = gid; e < NENT; e += stride) {
        float4 v = reinterpret_cast<const float4*>(tiles)[e * 16 + s];
        float sum = (v.x + v.y) + (v.z + v.w);
        sum += __shfl_xor(sum, 1);
        sum += __shfl_xor(sum, 2);
        sum += __shfl_xor(sum, 4);
        sum += __shfl_xor(sum, 8);
        if (s == 0) S[e] = sum;
    }
}

// Kernel 2: one block (256 thr) per batch element. Ballot-compact the valid
// indices (deterministic order), then 16x16-tiled double loop over pairs,
// gathering S[r*768+c] (table is L2-resident). Block reduce, write out[b].
__global__ __launch_bounds__(256) void k_pairs(const int* __restrict__ x,
                                               const int* __restrict__ turn,
                                               const float* __restrict__ S,
                                               float* __restrict__ out) {
    __shared__ int idx[64];
    __shared__ int s_cnt;
    __shared__ float wsum[4];

    const int b = blockIdx.x;
    const int t = threadIdx.x;
    const int white = turn[b];     // 1 -> white (zw), 0 -> black (zb)

    if (t < 64) {                  // wave 0 does the compaction
        int v = (t < NF) ? x[b * NF + t] : DIN;
        bool keep = (v < DIN) && (v != 3) && (white == 1 || v != 443);
        unsigned long long mk = __ballot(keep);
        if (keep) idx[__popcll(mk & ((1ull << t) - 1ull))] = v;
        if (t == 0) s_cnt = (int)__popcll(mk);
    }
    __syncthreads();

    const int m = s_cnt;
    float acc = 0.f;
    const int tx = t & 15, ty = t >> 4;
    for (int r = ty; r < m; r += 16) {
        const float* __restrict__ row = S + idx[r] * DIN;
        for (int c = tx; c < m; c += 16) acc += row[idx[c]];
    }

    // reduce across the 64-lane wave
    acc += __shfl_xor(acc, 1);
    acc += __shfl_xor(acc, 2);
    acc += __shfl_xor(acc, 4);
    acc += __shfl_xor(acc, 8);
    acc += __shfl_xor(acc, 16);
    acc += __shfl_xor(acc, 32);
    if ((t & 63) == 0) wsum[t >> 6] = acc;
    __syncthreads();
    if (t == 0) {
        out[b] = (wsum[0] + wsum[1]) + (wsum[2] + wsum[3]);
        if (b == 0) out[NB] = 0.f;   // second reference output: zeros(1)
    }
}

extern "C" void kernel_launch(void* const* d_in, const int* in_sizes, int n_in,
                              void* d_out, int out_size, void* d_ws, size_t ws_size,
                              hipStream_t stream) {
    const int*   x     = (const int*)d_in[0];     // (1024, 36) int32
    const int*   turn  = (const int*)d_in[1];     // (1024, 1) int32
    const float* tiles = (const float*)d_in[2];   // (12,8,8,12,8,8,64) f32
    float* out = (float*)d_out;                   // 1025 floats
    float* S   = (float*)d_ws;                    // 768*768 f32 scratch (2.36 MB)

    // 2048 blocks * 256 thr = 32768 groups of 16 lanes; 589824/32768 = 18
    // iterations each, no tail divergence. Fills all 256 CUs.
    k_rowsum<<<2048, 256, 0, stream>>>(tiles, S);
    k_pairs<<<NB, 256, 0, stream>>>(x, turn, S, out);
}